// Round 1
// baseline (33033.682 us; speedup 1.0000x reference)
//
#include <hip/hip_runtime.h>
#include <stdint.h>

// Problem constants
#define Bv 16
#define Sv 2048
#define Iv 128
#define Hv 512
#define Ov 128

typedef __bf16 v8bf __attribute__((ext_vector_type(8)));
typedef float v4f __attribute__((ext_vector_type(4)));

#define MFMA(a, b, c) __builtin_amdgcn_mfma_f32_16x16x32_bf16((a), (b), (c), 0, 0, 0)

__device__ __forceinline__ float sigf(float x) { return 1.0f / (1.0f + __expf(-x)); }
__device__ __forceinline__ float tanh_fast(float x) { return 2.0f / (1.0f + __expf(-2.0f * x)) - 1.0f; }

__device__ __forceinline__ v8bf cvt8(const float* p) {
  v8bf r;
#pragma unroll
  for (int i = 0; i < 8; i++) r[i] = (__bf16)p[i];
  return r;
}

// one thread spins (acquire, agent scope), rest wait at barrier
__device__ __forceinline__ void wgwait(unsigned* c, unsigned tgt) {
  if (threadIdx.x == 0) {
    unsigned iters = 0;
    while (__hip_atomic_load(c, __ATOMIC_ACQUIRE, __HIP_MEMORY_SCOPE_AGENT) < tgt) {
      if (++iters > (1u << 25)) break;  // safety valve: wrong answer beats GPU hang
    }
  }
  __syncthreads();
}

// all threads fence their stores, barrier, then one release-add
__device__ __forceinline__ void wgpost(unsigned* c) {
  __threadfence();
  __syncthreads();
  if (threadIdx.x == 0)
    __hip_atomic_fetch_add(c, 1u, __ATOMIC_RELEASE, __HIP_MEMORY_SCOPE_AGENT);
}

__global__ __launch_bounds__(256, 1) void gru_fused(
    const float* __restrict__ x, const float* __restrict__ hs,
    const float* __restrict__ Wxz0, const float* __restrict__ Whz0, const float* __restrict__ bhz0,
    const float* __restrict__ Wxr0, const float* __restrict__ Whr0, const float* __restrict__ bhr0,
    const float* __restrict__ Wxz1, const float* __restrict__ Whz1, const float* __restrict__ bhz1,
    const float* __restrict__ Wxr1, const float* __restrict__ Whr1, const float* __restrict__ bhr1,
    const float* __restrict__ Why, const float* __restrict__ by,
    float* __restrict__ out, char* __restrict__ ws, int D0) {
  const int tid = threadIdx.x;
  const int wave = tid >> 6;
  const int lane = tid & 63;
  const int lm = lane & 15;  // MFMA "index within 16"
  const int lq = lane >> 4;  // quad
  const int rb = tid >> 4;   // reduce-phase batch
  const int rj = tid & 15;   // reduce-phase j within slice

  unsigned* cnt_h0 = (unsigned*)ws;
  unsigned* cnt_u0 = (unsigned*)(ws + 128);
  unsigned* cnt_h1 = (unsigned*)(ws + 256);
  unsigned* cnt_u1 = (unsigned*)(ws + 384);
  __bf16* h0ring = (__bf16*)(ws + 1024);
  __bf16* h1ring = h0ring + (size_t)D0 * Bv * Hv;
  __bf16* u0ring = h1ring + 4 * Bv * Hv;
  __bf16* u1ring = u0ring + 2 * Bv * Hv;
  const int m0 = D0 - 1;

  __shared__ float red[4][4][16][16];  // [array][wave][b][j]

  const bool L0 = (blockIdx.x < 32);
  const int wg = L0 ? blockIdx.x : (blockIdx.x - 32);
  const int j0 = wg << 4;
  const bool OW = (!L0) && (wg < 8);  // out-head wgs own o-slice j0..j0+15 (o<128)

  // ---- initial hidden state into ring slot 0, then post ----
  {
    float h0v = hs[((size_t)rb * 2 + (L0 ? 0 : 1)) * Hv + j0 + rj];
    if (L0)
      h0ring[rb * Hv + j0 + rj] = (__bf16)h0v;
    else
      h1ring[rb * Hv + j0 + rj] = (__bf16)h0v;
    wgpost(L0 ? cnt_h0 : cnt_h1);
  }

  const int jrow = j0 + lm;

  if (L0) {
    // ---- resident weight fragments (bf16) ----
    v8bf wzx0 = cvt8(Wxz0 + (size_t)jrow * Iv + wave * 32 + lq * 8);
    v8bf wrx0 = cvt8(Wxr0 + (size_t)jrow * Iv + wave * 32 + lq * 8);
    v8bf wzh[4], wrh[4];
#pragma unroll
    for (int kb = 0; kb < 4; kb++) {
      int k = wave * 128 + kb * 32 + lq * 8;
      wzh[kb] = cvt8(Whz0 + (size_t)jrow * Hv + k);
      wrh[kb] = cvt8(Whr0 + (size_t)jrow * Hv + k);
    }
    float bz = bhz0[j0 + rj], br = bhr0[j0 + rj];

    const int xk = wave * 32 + lq * 8;
    float4 xp0 = *(const float4*)(x + ((size_t)lm * Sv + 0) * Iv + xk);
    float4 xp1 = *(const float4*)(x + ((size_t)lm * Sv + 0) * Iv + xk + 4);

    for (int t = 0; t < Sv; ++t) {
      // backpressure: don't overwrite y0 ring slots layer 1 hasn't consumed
      if (t + 3 > D0) wgwait(cnt_h1, 32u * (unsigned)(t + 3 - D0));
      wgwait(cnt_h0, 32u * (unsigned)(t + 1));
      const __bf16* hsl = h0ring + (size_t)(t & m0) * Bv * Hv;
      float hval = (float)hsl[rb * Hv + j0 + rj];
      v8bf ah[4];
#pragma unroll
      for (int kb = 0; kb < 4; kb++)
        ah[kb] = *(const v8bf*)(hsl + (size_t)lm * Hv + wave * 128 + kb * 32 + lq * 8);
      v8bf ax;
      {
        float xf[8] = {xp0.x, xp0.y, xp0.z, xp0.w, xp1.x, xp1.y, xp1.z, xp1.w};
#pragma unroll
        for (int i = 0; i < 8; i++) ax[i] = (__bf16)xf[i];
      }
      v4f az = {0, 0, 0, 0}, axr = {0, 0, 0, 0}, ahr = {0, 0, 0, 0};
      az = MFMA(ax, wzx0, az);
      axr = MFMA(ax, wrx0, axr);
#pragma unroll
      for (int kb = 0; kb < 4; kb++) {
        az = MFMA(ah[kb], wzh[kb], az);
        ahr = MFMA(ah[kb], wrh[kb], ahr);
      }
#pragma unroll
      for (int v = 0; v < 4; v++) {
        red[0][wave][lq * 4 + v][lm] = az[v];
        red[1][wave][lq * 4 + v][lm] = axr[v];
        red[2][wave][lq * 4 + v][lm] = ahr[v];
      }
      __syncthreads();
      float zs = 0, xrs = 0, hrs = 0;
#pragma unroll
      for (int w = 0; w < 4; w++) {
        zs += red[0][w][rb][rj];
        xrs += red[1][w][rb][rj];
        hrs += red[2][w][rb][rj];
      }
      float z = sigf(zs + bz);
      float r = sigf(xrs + hrs + br);
      u0ring[(size_t)(t & 1) * Bv * Hv + rb * Hv + j0 + rj] = (__bf16)(r * hval);
      if (t + 1 < Sv) {  // prefetch next x tile (off critical path)
        xp0 = *(const float4*)(x + ((size_t)lm * Sv + (t + 1)) * Iv + xk);
        xp1 = *(const float4*)(x + ((size_t)lm * Sv + (t + 1)) * Iv + xk + 4);
      }
      wgpost(cnt_u0);
      wgwait(cnt_u0, 32u * (unsigned)(t + 1));
      const __bf16* usl = u0ring + (size_t)(t & 1) * Bv * Hv;
      v8bf au[4];
#pragma unroll
      for (int kb = 0; kb < 4; kb++)
        au[kb] = *(const v8bf*)(usl + (size_t)lm * Hv + wave * 128 + kb * 32 + lq * 8);
      v4f ag = {0, 0, 0, 0};
#pragma unroll
      for (int kb = 0; kb < 4; kb++) ag = MFMA(au[kb], wrh[kb], ag);
#pragma unroll
      for (int v = 0; v < 4; v++) red[3][wave][lq * 4 + v][lm] = ag[v];
      __syncthreads();
      float gs = 0;
#pragma unroll
      for (int w = 0; w < 4; w++) gs += red[3][w][rb][rj];
      float g = tanh_fast(xrs + gs + br);  // faithful to source bug: reuses xr + bhr + Whr
      float hn = z * hval + (1.f - z) * g;
      h0ring[(size_t)((t + 1) & m0) * Bv * Hv + rb * Hv + j0 + rj] = (__bf16)hn;
      if (t == Sv - 1) out[(size_t)Bv * Sv * Ov + ((size_t)rb * 2 + 0) * Hv + j0 + rj] = hn;
      wgpost(cnt_h0);
    }
  } else {
    v8bf wzx1[4], wrx1[4], wzh[4], wrh[4], wo[4];
#pragma unroll
    for (int kb = 0; kb < 4; kb++) {
      int k = wave * 128 + kb * 32 + lq * 8;
      wzx1[kb] = cvt8(Wxz1 + (size_t)jrow * Hv + k);
      wrx1[kb] = cvt8(Wxr1 + (size_t)jrow * Hv + k);
      wzh[kb] = cvt8(Whz1 + (size_t)jrow * Hv + k);
      wrh[kb] = cvt8(Whr1 + (size_t)jrow * Hv + k);
      if (OW) wo[kb] = cvt8(Why + (size_t)jrow * Hv + k);
    }
    float bz = bhz1[j0 + rj], br = bhr1[j0 + rj];
    float bo = OW ? by[j0 + rj] : 0.f;

    for (int t = 0; t < Sv; ++t) {
      wgwait(cnt_h0, 32u * (unsigned)(t + 2));  // y0_t = h0 ring slot t+1
      wgwait(cnt_h1, 32u * (unsigned)(t + 1));
      const __bf16* ysl = h0ring + (size_t)((t + 1) & m0) * Bv * Hv;
      const __bf16* hsl = h1ring + (size_t)(t & 3) * Bv * Hv;
      float hval = (float)hsl[rb * Hv + j0 + rj];
      v8bf ay[4], ah[4];
#pragma unroll
      for (int kb = 0; kb < 4; kb++) {
        int k = wave * 128 + kb * 32 + lq * 8;
        ay[kb] = *(const v8bf*)(ysl + (size_t)lm * Hv + k);
        ah[kb] = *(const v8bf*)(hsl + (size_t)lm * Hv + k);
      }
      v4f az = {0, 0, 0, 0}, axr = {0, 0, 0, 0}, ahr = {0, 0, 0, 0}, ao = {0, 0, 0, 0};
#pragma unroll
      for (int kb = 0; kb < 4; kb++) {
        az = MFMA(ay[kb], wzx1[kb], az);
        az = MFMA(ah[kb], wzh[kb], az);
        axr = MFMA(ay[kb], wrx1[kb], axr);
        ahr = MFMA(ah[kb], wrh[kb], ahr);
      }
      if (OW && t > 0) {
#pragma unroll
        for (int kb = 0; kb < 4; kb++) ao = MFMA(ah[kb], wo[kb], ao);  // out_{t-1} from y1_{t-1}
      }
#pragma unroll
      for (int v = 0; v < 4; v++) {
        red[0][wave][lq * 4 + v][lm] = az[v];
        red[1][wave][lq * 4 + v][lm] = axr[v];
        red[2][wave][lq * 4 + v][lm] = ahr[v];
        red[3][wave][lq * 4 + v][lm] = ao[v];
      }
      __syncthreads();
      float zs = 0, xrs = 0, hrs = 0, os = 0;
#pragma unroll
      for (int w = 0; w < 4; w++) {
        zs += red[0][w][rb][rj];
        xrs += red[1][w][rb][rj];
        hrs += red[2][w][rb][rj];
        os += red[3][w][rb][rj];
      }
      float z = sigf(zs + bz);
      float r = sigf(xrs + hrs + br);
      u1ring[(size_t)(t & 1) * Bv * Hv + rb * Hv + j0 + rj] = (__bf16)(r * hval);
      if (OW && t > 0) out[((size_t)rb * Sv + (t - 1)) * Ov + j0 + rj] = os + bo;
      wgpost(cnt_u1);
      wgwait(cnt_u1, 32u * (unsigned)(t + 1));
      const __bf16* usl = u1ring + (size_t)(t & 1) * Bv * Hv;
      v8bf au[4];
#pragma unroll
      for (int kb = 0; kb < 4; kb++)
        au[kb] = *(const v8bf*)(usl + (size_t)lm * Hv + wave * 128 + kb * 32 + lq * 8);
      v4f ag = {0, 0, 0, 0};
#pragma unroll
      for (int kb = 0; kb < 4; kb++) ag = MFMA(au[kb], wrh[kb], ag);
#pragma unroll
      for (int v = 0; v < 4; v++) red[3][wave][lq * 4 + v][lm] = ag[v];
      __syncthreads();
      float gs = 0;
#pragma unroll
      for (int w = 0; w < 4; w++) gs += red[3][w][rb][rj];
      float g = tanh_fast(xrs + gs + br);
      float hn = z * hval + (1.f - z) * g;
      h1ring[(size_t)((t + 1) & 3) * Bv * Hv + rb * Hv + j0 + rj] = (__bf16)hn;
      if (t == Sv - 1) out[(size_t)Bv * Sv * Ov + ((size_t)rb * 2 + 1) * Hv + j0 + rj] = hn;
      wgpost(cnt_h1);
    }
    if (OW) {  // tail: out for t = S-1 uses y1_{S-1} = h1 ring slot S
      wgwait(cnt_h1, 32u * (unsigned)(Sv + 1));
      const __bf16* hsl = h1ring + (size_t)(Sv & 3) * Bv * Hv;
      v8bf ah[4];
#pragma unroll
      for (int kb = 0; kb < 4; kb++)
        ah[kb] = *(const v8bf*)(hsl + (size_t)lm * Hv + wave * 128 + kb * 32 + lq * 8);
      v4f ao = {0, 0, 0, 0};
#pragma unroll
      for (int kb = 0; kb < 4; kb++) ao = MFMA(ah[kb], wo[kb], ao);
#pragma unroll
      for (int v = 0; v < 4; v++) red[3][wave][lq * 4 + v][lm] = ao[v];
      __syncthreads();
      float os = 0;
#pragma unroll
      for (int w = 0; w < 4; w++) os += red[3][w][rb][rj];
      out[((size_t)rb * Sv + (Sv - 1)) * Ov + j0 + rj] = os + bo;
    }
  }
}

extern "C" void kernel_launch(void* const* d_in, const int* in_sizes, int n_in,
                              void* d_out, int out_size, void* d_ws, size_t ws_size,
                              hipStream_t stream) {
  const float* x = (const float*)d_in[0];
  const float* hs = (const float*)d_in[1];
  const float* Wxz0 = (const float*)d_in[2];
  const float* Whz0 = (const float*)d_in[3];
  const float* bhz0 = (const float*)d_in[4];
  const float* Wxr0 = (const float*)d_in[5];
  const float* Whr0 = (const float*)d_in[6];
  const float* bhr0 = (const float*)d_in[7];
  const float* Wxz1 = (const float*)d_in[8];
  const float* Whz1 = (const float*)d_in[9];
  const float* bhz1 = (const float*)d_in[10];
  const float* Wxr1 = (const float*)d_in[11];
  const float* Whr1 = (const float*)d_in[12];
  const float* bhr1 = (const float*)d_in[13];
  const float* Why = (const float*)d_in[14];
  const float* by = (const float*)d_in[15];
  float* out = (float*)d_out;

  // pick largest pow2 y0-ring depth that fits ws
  int D0 = 256;
  while (D0 > 4 && (size_t)(1024 + (size_t)D0 * 16384 + 131072) > ws_size) D0 >>= 1;

  hipMemsetAsync(d_ws, 0, 512, stream);  // zero the sync counters
  hipLaunchKernelGGL(gru_fused, dim3(64), dim3(256), 0, stream,
                     x, hs, Wxz0, Whz0, bhz0, Wxr0, Whr0, bhr0,
                     Wxz1, Whz1, bhz1, Wxr1, Whr1, bhr1, Why, by,
                     out, (char*)d_ws, D0);
}

// Round 2
// 13115.170 us; speedup vs baseline: 2.5187x; 2.5187x over previous
//
#include <hip/hip_runtime.h>
#include <stdint.h>

// Problem constants
#define Bv 16
#define Sv 2048
#define Iv 128
#define Hv 512
#define Ov 128
#define RP 520  // staged LDS row pitch in ushorts (512 + 8 pad for bank spread)

typedef __bf16 v8bf __attribute__((ext_vector_type(8)));
typedef float v4f __attribute__((ext_vector_type(4)));
#define MFMA(a, b, c) __builtin_amdgcn_mfma_f32_16x16x32_bf16((a), (b), (c), 0, 0, 0)

__device__ __forceinline__ float sigf(float x) { return 1.0f / (1.0f + __expf(-x)); }
__device__ __forceinline__ float tanh_fast(float x) { return 2.0f / (1.0f + __expf(-2.0f * x)) - 1.0f; }

__device__ __forceinline__ unsigned short f2bf(float f) {
  union { __bf16 h; unsigned short u; } c; c.h = (__bf16)f; return c.u;
}
__device__ __forceinline__ float bf2f(unsigned short u) {
  union { __bf16 h; unsigned short u; } c; c.u = u; return (float)c.h;
}

__device__ __forceinline__ v8bf cvt8(const float* p) {
  v8bf r;
#pragma unroll
  for (int i = 0; i < 8; i++) r[i] = (__bf16)p[i];
  return r;
}

// relaxed agent-scope atomics: lower to sc1 (bypass non-coherent per-XCD L2),
// NO cache invalidate/writeback ops — this is the whole point.
__device__ __forceinline__ uint64_t ld64(const uint64_t* p) {
  return __hip_atomic_load((uint64_t*)p, __ATOMIC_RELAXED, __HIP_MEMORY_SCOPE_AGENT);
}
__device__ __forceinline__ void st32(unsigned* p, unsigned v) {
  __hip_atomic_store(p, v, __ATOMIC_RELAXED, __HIP_MEMORY_SCOPE_AGENT);
}
__device__ __forceinline__ unsigned ld32(const unsigned* p) {
  return __hip_atomic_load((unsigned*)p, __ATOMIC_RELAXED, __HIP_MEMORY_SCOPE_AGENT);
}

// Poll one 16x512-word ring slot (word = tag16<<16 | bf16bits) until every
// tag == want; stage values into lds[16][RP]. Batched loads: one memory
// round-trip per retry round, not per word.
__device__ __forceinline__ void poll_stage(const unsigned* slot, unsigned want,
                                           unsigned short* lds, int tid) {
  const uint64_t* p = (const uint64_t*)slot;
  const uint64_t pat = ((uint64_t)want << 16) | ((uint64_t)want << 48);
  uint64_t w[16];
#pragma unroll
  for (int i = 0; i < 16; i++) w[i] = ld64(p + i * 256 + tid);
  for (unsigned r = 0;;) {
    bool any = false;
#pragma unroll
    for (int i = 0; i < 16; i++)
      if ((w[i] & 0xffff0000ffff0000ull) != pat) { w[i] = ld64(p + i * 256 + tid); any = true; }
    if (!any || ++r > (1u << 20)) break;  // valve: wrong answer beats hang
  }
#pragma unroll
  for (int i = 0; i < 16; i++) {  // u64 idx i*256+tid -> b=i, k=2*tid
    lds[i * RP + tid * 2] = (unsigned short)w[i];
    lds[i * RP + tid * 2 + 1] = (unsigned short)(w[i] >> 32);
  }
}

// Dual-slot poll: both batches in flight together (single round-trip).
__device__ __forceinline__ void poll_stage2(const unsigned* sA, unsigned wantA, unsigned short* lA,
                                            const unsigned* sB, unsigned wantB, unsigned short* lB,
                                            int tid) {
  const uint64_t* pA = (const uint64_t*)sA;
  const uint64_t* pB = (const uint64_t*)sB;
  const uint64_t patA = ((uint64_t)wantA << 16) | ((uint64_t)wantA << 48);
  const uint64_t patB = ((uint64_t)wantB << 16) | ((uint64_t)wantB << 48);
  uint64_t wa[16], wb[16];
#pragma unroll
  for (int i = 0; i < 16; i++) wa[i] = ld64(pA + i * 256 + tid);
#pragma unroll
  for (int i = 0; i < 16; i++) wb[i] = ld64(pB + i * 256 + tid);
  for (unsigned r = 0;;) {
    bool any = false;
#pragma unroll
    for (int i = 0; i < 16; i++)
      if ((wa[i] & 0xffff0000ffff0000ull) != patA) { wa[i] = ld64(pA + i * 256 + tid); any = true; }
#pragma unroll
    for (int i = 0; i < 16; i++)
      if ((wb[i] & 0xffff0000ffff0000ull) != patB) { wb[i] = ld64(pB + i * 256 + tid); any = true; }
    if (!any || ++r > (1u << 20)) break;
  }
#pragma unroll
  for (int i = 0; i < 16; i++) {
    lA[i * RP + tid * 2] = (unsigned short)wa[i];
    lA[i * RP + tid * 2 + 1] = (unsigned short)(wa[i] >> 32);
    lB[i * RP + tid * 2] = (unsigned short)wb[i];
    lB[i * RP + tid * 2 + 1] = (unsigned short)(wb[i] >> 32);
  }
}

__global__ __launch_bounds__(256, 1) void gru_fused(
    const float* __restrict__ x, const float* __restrict__ hs,
    const float* __restrict__ Wxz0, const float* __restrict__ Whz0, const float* __restrict__ bhz0,
    const float* __restrict__ Wxr0, const float* __restrict__ Whr0, const float* __restrict__ bhr0,
    const float* __restrict__ Wxz1, const float* __restrict__ Whz1, const float* __restrict__ bhz1,
    const float* __restrict__ Wxr1, const float* __restrict__ Whr1, const float* __restrict__ bhr1,
    const float* __restrict__ Why, const float* __restrict__ by,
    float* __restrict__ out, char* __restrict__ ws, int D) {
  const int tid = threadIdx.x;
  const int wave = tid >> 6;
  const int lane = tid & 63;
  const int lm = lane & 15;  // MFMA index-within-16
  const int lq = lane >> 4;  // quad
  const int rb = tid >> 4;   // reduce-phase batch
  const int rj = tid & 15;   // reduce-phase j within slice
  const int m0 = D - 1;

  unsigned* prog = (unsigned*)ws;  // [32] layer-1 progress (zeroed by memset)
  unsigned* h0r = (unsigned*)(ws + 4096);        // D * 8192 words
  unsigned* h1r = h0r + (size_t)D * 8192;        // 4 * 8192
  unsigned* u0r = h1r + 4 * 8192;                // 2 * 8192
  unsigned* u1r = u0r + 2 * 8192;                // 2 * 8192

  __shared__ unsigned short stA[16 * RP];  // h0/y0 stage
  __shared__ unsigned short stB[16 * RP];  // u0 / h1 stage
  __shared__ unsigned short stC[16 * RP];  // u1 stage (L1 only)
  __shared__ float red[4][4][16][17];      // [array][wave][b][j] (+1 pad)

  const bool L0 = (blockIdx.x < 32);
  const int wg = L0 ? blockIdx.x : (blockIdx.x - 32);
  const int j0 = wg << 4;
  const bool OW = (!L0) && (wg < 8);
  const int jrow = j0 + lm;

  // ---- initial hidden state -> ring slot 0 with tag 1 ----
  {
    float h0v = hs[((size_t)rb * 2 + (L0 ? 0 : 1)) * Hv + j0 + rj];
    unsigned word = (1u << 16) | f2bf(h0v);
    st32((L0 ? h0r : h1r) + rb * 512 + j0 + rj, word);
  }

  if (L0) {
    v8bf wzx0 = cvt8(Wxz0 + (size_t)jrow * Iv + wave * 32 + lq * 8);
    v8bf wrx0 = cvt8(Wxr0 + (size_t)jrow * Iv + wave * 32 + lq * 8);
    v8bf wzh[4], wrh[4];
#pragma unroll
    for (int kb = 0; kb < 4; kb++) {
      int k = wave * 128 + kb * 32 + lq * 8;
      wzh[kb] = cvt8(Whz0 + (size_t)jrow * Hv + k);
      wrh[kb] = cvt8(Whr0 + (size_t)jrow * Hv + k);
    }
    float bz = bhz0[j0 + rj], br = bhr0[j0 + rj];

    const int xk = wave * 32 + lq * 8;
    float4 xp0 = *(const float4*)(x + ((size_t)lm * Sv + 0) * Iv + xk);
    float4 xp1 = *(const float4*)(x + ((size_t)lm * Sv + 0) * Iv + xk + 4);

    for (int t = 0; t < Sv; ++t) {
      // backpressure vs layer-1 consumption of the y0 ring
      if (t >= D - 1 && tid < 32) {
        unsigned need = (unsigned)(t - D + 2);
        unsigned it = 0;
        while (ld32(prog + tid) < need)
          if (++it > (1u << 20)) break;
      }
      poll_stage(h0r + (size_t)(t & m0) * 8192, (unsigned)(t + 1), stA, tid);
      __syncthreads();
      float hval = bf2f(stA[rb * RP + j0 + rj]);
      const unsigned short* hrow = stA + lm * RP;
      v8bf ah[4];
#pragma unroll
      for (int kb = 0; kb < 4; kb++)
        ah[kb] = *(const v8bf*)(hrow + wave * 128 + kb * 32 + lq * 8);
      v8bf ax;
      {
        float xf[8] = {xp0.x, xp0.y, xp0.z, xp0.w, xp1.x, xp1.y, xp1.z, xp1.w};
#pragma unroll
        for (int i = 0; i < 8; i++) ax[i] = (__bf16)xf[i];
      }
      v4f az = {0, 0, 0, 0}, axr = {0, 0, 0, 0}, ahr = {0, 0, 0, 0};
      az = MFMA(ax, wzx0, az);
      axr = MFMA(ax, wrx0, axr);
#pragma unroll
      for (int kb = 0; kb < 4; kb++) {
        az = MFMA(ah[kb], wzh[kb], az);
        ahr = MFMA(ah[kb], wrh[kb], ahr);
      }
#pragma unroll
      for (int v = 0; v < 4; v++) {
        red[0][wave][lq * 4 + v][lm] = az[v];
        red[1][wave][lq * 4 + v][lm] = axr[v];
        red[2][wave][lq * 4 + v][lm] = ahr[v];
      }
      __syncthreads();
      float zs = 0, xrs = 0, hrs = 0;
#pragma unroll
      for (int w = 0; w < 4; w++) {
        zs += red[0][w][rb][rj];
        xrs += red[1][w][rb][rj];
        hrs += red[2][w][rb][rj];
      }
      float z = sigf(zs + bz);
      float r = sigf(xrs + hrs + br);
      st32(u0r + (size_t)(t & 1) * 8192 + rb * 512 + j0 + rj,
           ((unsigned)(t + 1) << 16) | f2bf(r * hval));
      if (t + 1 < Sv) {
        xp0 = *(const float4*)(x + ((size_t)lm * Sv + (t + 1)) * Iv + xk);
        xp1 = *(const float4*)(x + ((size_t)lm * Sv + (t + 1)) * Iv + xk + 4);
      }
      poll_stage(u0r + (size_t)(t & 1) * 8192, (unsigned)(t + 1), stB, tid);
      __syncthreads();
      const unsigned short* urow = stB + lm * RP;
      v4f ag = {0, 0, 0, 0};
#pragma unroll
      for (int kb = 0; kb < 4; kb++) {
        v8bf au = *(const v8bf*)(urow + wave * 128 + kb * 32 + lq * 8);
        ag = MFMA(au, wrh[kb], ag);
      }
#pragma unroll
      for (int v = 0; v < 4; v++) red[3][wave][lq * 4 + v][lm] = ag[v];
      __syncthreads();
      float gs = 0;
#pragma unroll
      for (int w = 0; w < 4; w++) gs += red[3][w][rb][rj];
      float g = tanh_fast(xrs + gs + br);  // faithful to source bug
      float hn = z * hval + (1.f - z) * g;
      st32(h0r + (size_t)((t + 1) & m0) * 8192 + rb * 512 + j0 + rj,
           ((unsigned)(t + 2) << 16) | f2bf(hn));
      if (t == Sv - 1) out[(size_t)Bv * Sv * Ov + ((size_t)rb * 2 + 0) * Hv + j0 + rj] = hn;
    }
  } else {
    v8bf wzx1[4], wrx1[4], wzh[4], wrh[4], wo[4];
#pragma unroll
    for (int kb = 0; kb < 4; kb++) {
      int k = wave * 128 + kb * 32 + lq * 8;
      wzx1[kb] = cvt8(Wxz1 + (size_t)jrow * Hv + k);
      wrx1[kb] = cvt8(Wxr1 + (size_t)jrow * Hv + k);
      wzh[kb] = cvt8(Whz1 + (size_t)jrow * Hv + k);
      wrh[kb] = cvt8(Whr1 + (size_t)jrow * Hv + k);
      if (OW) wo[kb] = cvt8(Why + (size_t)jrow * Hv + k);
    }
    float bz = bhz1[j0 + rj], br = bhr1[j0 + rj];
    float bo = OW ? by[j0 + rj] : 0.f;

    for (int t = 0; t < Sv; ++t) {
      // y0_t = h0 ring tag t+2 at slot (t+1)%D; h1_t = tag t+1 at slot t&3
      poll_stage2(h0r + (size_t)((t + 1) & m0) * 8192, (unsigned)(t + 2), stA,
                  h1r + (size_t)(t & 3) * 8192, (unsigned)(t + 1), stB, tid);
      __syncthreads();
      if (tid == 0) st32(prog + wg, (unsigned)(t + 1));  // y0_t consumed
      float hval = bf2f(stB[rb * RP + j0 + rj]);
      const unsigned short* yrow = stA + lm * RP;
      const unsigned short* hrow = stB + lm * RP;
      v4f az = {0, 0, 0, 0}, axr = {0, 0, 0, 0}, ahr = {0, 0, 0, 0}, ao = {0, 0, 0, 0};
      v8bf ahf[4];
#pragma unroll
      for (int kb = 0; kb < 4; kb++) {
        int k = wave * 128 + kb * 32 + lq * 8;
        v8bf ay = *(const v8bf*)(yrow + k);
        ahf[kb] = *(const v8bf*)(hrow + k);
        az = MFMA(ay, wzx1[kb], az);
        az = MFMA(ahf[kb], wzh[kb], az);
        axr = MFMA(ay, wrx1[kb], axr);
        ahr = MFMA(ahf[kb], wrh[kb], ahr);
      }
      if (OW && t > 0) {
#pragma unroll
        for (int kb = 0; kb < 4; kb++) ao = MFMA(ahf[kb], wo[kb], ao);  // out_{t-1}
      }
#pragma unroll
      for (int v = 0; v < 4; v++) {
        red[0][wave][lq * 4 + v][lm] = az[v];
        red[1][wave][lq * 4 + v][lm] = axr[v];
        red[2][wave][lq * 4 + v][lm] = ahr[v];
        red[3][wave][lq * 4 + v][lm] = ao[v];
      }
      __syncthreads();
      float zs = 0, xrs = 0, hrs = 0, os = 0;
#pragma unroll
      for (int w = 0; w < 4; w++) {
        zs += red[0][w][rb][rj];
        xrs += red[1][w][rb][rj];
        hrs += red[2][w][rb][rj];
        os += red[3][w][rb][rj];
      }
      float z = sigf(zs + bz);
      float r = sigf(xrs + hrs + br);
      st32(u1r + (size_t)(t & 1) * 8192 + rb * 512 + j0 + rj,
           ((unsigned)(t + 1) << 16) | f2bf(r * hval));
      if (OW && t > 0) out[((size_t)rb * Sv + (t - 1)) * Ov + j0 + rj] = os + bo;
      poll_stage(u1r + (size_t)(t & 1) * 8192, (unsigned)(t + 1), stC, tid);
      __syncthreads();
      const unsigned short* urow = stC + lm * RP;
      v4f ag = {0, 0, 0, 0};
#pragma unroll
      for (int kb = 0; kb < 4; kb++) {
        v8bf au = *(const v8bf*)(urow + wave * 128 + kb * 32 + lq * 8);
        ag = MFMA(au, wrh[kb], ag);
      }
#pragma unroll
      for (int v = 0; v < 4; v++) red[3][wave][lq * 4 + v][lm] = ag[v];
      __syncthreads();
      float gs = 0;
#pragma unroll
      for (int w = 0; w < 4; w++) gs += red[3][w][rb][rj];
      float g = tanh_fast(xrs + gs + br);
      float hn = z * hval + (1.f - z) * g;
      st32(h1r + (size_t)((t + 1) & 3) * 8192 + rb * 512 + j0 + rj,
           ((unsigned)(t + 2) << 16) | f2bf(hn));
      if (t == Sv - 1) out[(size_t)Bv * Sv * Ov + ((size_t)rb * 2 + 1) * Hv + j0 + rj] = hn;
    }
    if (OW) {  // tail: out_{S-1} from y1_{S-1} = h1 tag S+1 at slot S&3
      poll_stage(h1r + (size_t)(Sv & 3) * 8192, (unsigned)(Sv + 1), stB, tid);
      __syncthreads();
      const unsigned short* hrow = stB + lm * RP;
      v4f ao = {0, 0, 0, 0};
#pragma unroll
      for (int kb = 0; kb < 4; kb++) {
        v8bf ah = *(const v8bf*)(hrow + wave * 128 + kb * 32 + lq * 8);
        ao = MFMA(ah, wo[kb], ao);
      }
#pragma unroll
      for (int v = 0; v < 4; v++) red[3][wave][lq * 4 + v][lm] = ao[v];
      __syncthreads();
      float os = 0;
#pragma unroll
      for (int w = 0; w < 4; w++) os += red[3][w][rb][rj];
      out[((size_t)rb * Sv + (Sv - 1)) * Ov + j0 + rj] = os + bo;
    }
  }
}

extern "C" void kernel_launch(void* const* d_in, const int* in_sizes, int n_in,
                              void* d_out, int out_size, void* d_ws, size_t ws_size,
                              hipStream_t stream) {
  const float* x = (const float*)d_in[0];
  const float* hs = (const float*)d_in[1];
  const float* Wxz0 = (const float*)d_in[2];
  const float* Whz0 = (const float*)d_in[3];
  const float* bhz0 = (const float*)d_in[4];
  const float* Wxr0 = (const float*)d_in[5];
  const float* Whr0 = (const float*)d_in[6];
  const float* bhr0 = (const float*)d_in[7];
  const float* Wxz1 = (const float*)d_in[8];
  const float* Whz1 = (const float*)d_in[9];
  const float* bhz1 = (const float*)d_in[10];
  const float* Wxr1 = (const float*)d_in[11];
  const float* Whr1 = (const float*)d_in[12];
  const float* bhr1 = (const float*)d_in[13];
  const float* Why = (const float*)d_in[14];
  const float* by = (const float*)d_in[15];
  float* out = (float*)d_out;

  // y0-ring depth: largest pow2 (<=64, >=4) fitting ws
  int D = 64;
  while (D > 4 && 4096 + (size_t)(D + 8) * 32768 > ws_size) D >>= 1;

  hipMemsetAsync(d_ws, 0, 4096, stream);  // zero progress words
  hipLaunchKernelGGL(gru_fused, dim3(64), dim3(256), 0, stream,
                     x, hs, Wxz0, Whz0, bhz0, Wxr0, Whr0, bhr0,
                     Wxz1, Whz1, bhz1, Wxr1, Whr1, bhr1, Why, by,
                     out, (char*)d_ws, D);
}

// Round 3
// 9003.506 us; speedup vs baseline: 3.6690x; 1.4567x over previous
//
#include <hip/hip_runtime.h>
#include <stdint.h>

// Problem constants
#define Bv 16
#define Sv 2048
#define Iv 128
#define Hv 512
#define Ov 128
#define RP 520  // staged LDS row pitch in ushorts

typedef __bf16 v8bf __attribute__((ext_vector_type(8)));
typedef float v4f __attribute__((ext_vector_type(4)));
#define MFMA(a, b, c) __builtin_amdgcn_mfma_f32_16x16x32_bf16((a), (b), (c), 0, 0, 0)

__device__ __forceinline__ float sigf(float x) { return 1.0f / (1.0f + __expf(-x)); }
__device__ __forceinline__ float tanh_fast(float x) { return 2.0f / (1.0f + __expf(-2.0f * x)) - 1.0f; }

__device__ __forceinline__ unsigned f2bf(float f) {
  union { __bf16 h; unsigned short u; } c; c.h = (__bf16)f; return (unsigned)c.u;
}
__device__ __forceinline__ float bf2f(unsigned short u) {
  union { __bf16 h; unsigned short u; } c; c.u = u; return (float)c.h;
}

__device__ __forceinline__ v8bf cvt8(const float* p) {
  v8bf r;
#pragma unroll
  for (int i = 0; i < 8; i++) r[i] = (__bf16)p[i];
  return r;
}

// relaxed agent-scope atomics (sc1: bypass non-coherent per-XCD L2, no cache
// maintenance ops). Coherence point = Infinity Cache.
__device__ __forceinline__ uint64_t ld64(const uint64_t* p) {
  return __hip_atomic_load((uint64_t*)p, __ATOMIC_RELAXED, __HIP_MEMORY_SCOPE_AGENT);
}
__device__ __forceinline__ void st32(unsigned* p, unsigned v) {
  __hip_atomic_store(p, v, __ATOMIC_RELAXED, __HIP_MEMORY_SCOPE_AGENT);
}
__device__ __forceinline__ unsigned ld32(const unsigned* p) {
  return __hip_atomic_load((unsigned*)p, __ATOMIC_RELAXED, __HIP_MEMORY_SCOPE_AGENT);
}

// Producer-side: pack this thread's bf16 with its rj-neighbor's, even threads
// store one u32. Slot data layout: u32[rb*256 + col/2], col-major-in-pairs.
__device__ __forceinline__ void store_slice(unsigned* dslot, int rb, int j0, int rj, float val) {
  unsigned bits = f2bf(val);
  unsigned nb = (unsigned)__shfl_xor((int)bits, 1);
  if ((rj & 1) == 0)
    st32(dslot + rb * 256 + ((j0 + rj) >> 1), bits | (nb << 16));
}

// Poll 32 sentinel words (128 B) until all == want. Retry round = ONE 4B load.
__device__ __forceinline__ void poll1(const unsigned* s, unsigned want, int tid) {
  unsigned r = 0;
  for (;;) {
    unsigned v = ld32(s + (tid & 31));
    if (__all(v == want) || ++r > (1u << 20)) break;  // valve: wrong beats hang
  }
}
__device__ __forceinline__ void poll2(const unsigned* sA, unsigned wA,
                                      const unsigned* sB, unsigned wB, int tid) {
  unsigned r = 0;
  for (;;) {
    unsigned a = ld32(sA + (tid & 31));
    unsigned b = ld32(sB + (tid & 31));
    if (__all((a == wA) && (b == wB)) || ++r > (1u << 20)) break;
  }
}

// One-shot payload read (16 KB, coalesced u64) -> LDS [16][RP] ushort rows.
__device__ __forceinline__ void read_stage(const unsigned* dslot, unsigned short* lds, int tid) {
  const uint64_t* p = (const uint64_t*)dslot;
  uint64_t w[8];
#pragma unroll
  for (int i = 0; i < 8; i++) w[i] = ld64(p + i * 256 + tid);
#pragma unroll
  for (int i = 0; i < 8; i++) {
    int d = i * 256 + tid;  // u64 index: b = d>>7, col = (d&127)*4
    *(uint64_t*)(lds + (d >> 7) * RP + (d & 127) * 4) = w[i];
  }
}
__device__ __forceinline__ void read_stage2(const unsigned* dA, unsigned short* lA,
                                            const unsigned* dB, unsigned short* lB, int tid) {
  const uint64_t* pA = (const uint64_t*)dA;
  const uint64_t* pB = (const uint64_t*)dB;
  uint64_t wa[8], wb[8];
#pragma unroll
  for (int i = 0; i < 8; i++) wa[i] = ld64(pA + i * 256 + tid);
#pragma unroll
  for (int i = 0; i < 8; i++) wb[i] = ld64(pB + i * 256 + tid);
#pragma unroll
  for (int i = 0; i < 8; i++) {
    int d = i * 256 + tid;
    *(uint64_t*)(lA + (d >> 7) * RP + (d & 127) * 4) = wa[i];
    *(uint64_t*)(lB + (d >> 7) * RP + (d & 127) * 4) = wb[i];
  }
}

__global__ __launch_bounds__(256, 1) void gru_fused(
    const float* __restrict__ x, const float* __restrict__ hs,
    const float* __restrict__ Wxz0, const float* __restrict__ Whz0, const float* __restrict__ bhz0,
    const float* __restrict__ Wxr0, const float* __restrict__ Whr0, const float* __restrict__ bhr0,
    const float* __restrict__ Wxz1, const float* __restrict__ Whz1, const float* __restrict__ bhz1,
    const float* __restrict__ Wxr1, const float* __restrict__ Whr1, const float* __restrict__ bhr1,
    const float* __restrict__ Why, const float* __restrict__ by,
    float* __restrict__ out, char* __restrict__ ws, int D) {
  const int tid = threadIdx.x;
  const int wave = tid >> 6;
  const int lane = tid & 63;
  const int lm = lane & 15;
  const int lq = lane >> 4;
  const int rb = tid >> 4;
  const int rj = tid & 15;
  const int m0 = D - 1;

  unsigned* prog = (unsigned*)ws;  // [32], zeroed by memset
  unsigned* h0s = (unsigned*)(ws + 1024);  // [D][32] sentinels
  unsigned* h1s = h0s + D * 32;            // [4][32]
  unsigned* u0s = h1s + 128;               // [2][32]
  unsigned* u1s = u0s + 64;                // [2][32]
  unsigned* h0d = (unsigned*)(ws + 16384); // [D][4096] payload (16KB/slot)
  unsigned* h1d = h0d + (size_t)D * 4096;  // [4][4096]
  unsigned* u0d = h1d + 4 * 4096;          // [2][4096]
  unsigned* u1d = u0d + 2 * 4096;          // [2][4096]

  __shared__ unsigned short stA[16 * RP];
  __shared__ unsigned short stB[16 * RP];
  __shared__ unsigned short stC[16 * RP];
  __shared__ float red[4][4][16][17];

  const bool L0 = (blockIdx.x < 32);
  const int wg = L0 ? blockIdx.x : (blockIdx.x - 32);
  const int j0 = wg << 4;
  const bool OW = (!L0) && (wg < 8);
  const int jrow = j0 + lm;

  // ---- initial hidden state -> payload slot 0, sentinel tag 1 ----
  {
    float h0v = hs[((size_t)rb * 2 + (L0 ? 0 : 1)) * Hv + j0 + rj];
    store_slice(L0 ? h0d : h1d, rb, j0, rj, h0v);
    __syncthreads();  // barrier drain = vmcnt(0): payload ack'd before sentinel
    if (tid == 0) st32((L0 ? h0s : h1s) + wg, 1u);
  }

  if (L0) {
    v8bf wzx0 = cvt8(Wxz0 + (size_t)jrow * Iv + wave * 32 + lq * 8);
    v8bf wrx0 = cvt8(Wxr0 + (size_t)jrow * Iv + wave * 32 + lq * 8);
    v8bf wzh[4], wrh[4];
#pragma unroll
    for (int kb = 0; kb < 4; kb++) {
      int k = wave * 128 + kb * 32 + lq * 8;
      wzh[kb] = cvt8(Whz0 + (size_t)jrow * Hv + k);
      wrh[kb] = cvt8(Whr0 + (size_t)jrow * Hv + k);
    }
    float bz = bhz0[j0 + rj], br = bhr0[j0 + rj];

    const int xk = wave * 32 + lq * 8;
    float4 xp0 = *(const float4*)(x + ((size_t)lm * Sv + 0) * Iv + xk);
    float4 xp1 = *(const float4*)(x + ((size_t)lm * Sv + 0) * Iv + xk + 4);

    for (int t = 0; t < Sv; ++t) {
      if (t >= D - 1 && tid < 32) {  // backpressure vs L1's y0 consumption
        unsigned need = (unsigned)(t - D + 2), it = 0;
        while (ld32(prog + tid) < need)
          if (++it > (1u << 20)) break;
      }
      poll1(h0s + (t & m0) * 32, (unsigned)(t + 1), tid);
      read_stage(h0d + (size_t)(t & m0) * 4096, stA, tid);
      __syncthreads();
      float hval = bf2f(stA[rb * RP + j0 + rj]);
      const unsigned short* hrow = stA + lm * RP;
      v8bf ah[4];
#pragma unroll
      for (int kb = 0; kb < 4; kb++)
        ah[kb] = *(const v8bf*)(hrow + wave * 128 + kb * 32 + lq * 8);
      v8bf ax;
      {
        float xf[8] = {xp0.x, xp0.y, xp0.z, xp0.w, xp1.x, xp1.y, xp1.z, xp1.w};
#pragma unroll
        for (int i = 0; i < 8; i++) ax[i] = (__bf16)xf[i];
      }
      v4f az = {0, 0, 0, 0}, axr = {0, 0, 0, 0}, ahr = {0, 0, 0, 0};
      az = MFMA(ax, wzx0, az);
      axr = MFMA(ax, wrx0, axr);
#pragma unroll
      for (int kb = 0; kb < 4; kb++) {
        az = MFMA(ah[kb], wzh[kb], az);
        ahr = MFMA(ah[kb], wrh[kb], ahr);
      }
#pragma unroll
      for (int v = 0; v < 4; v++) {
        red[0][wave][lq * 4 + v][lm] = az[v];
        red[1][wave][lq * 4 + v][lm] = axr[v];
        red[2][wave][lq * 4 + v][lm] = ahr[v];
      }
      __syncthreads();
      float zs = 0, xrs = 0, hrs = 0;
#pragma unroll
      for (int w = 0; w < 4; w++) {
        zs += red[0][w][rb][rj];
        xrs += red[1][w][rb][rj];
        hrs += red[2][w][rb][rj];
      }
      float z = sigf(zs + bz);
      float r = sigf(xrs + hrs + br);
      store_slice(u0d + (t & 1) * 4096, rb, j0, rj, r * hval);
      if (t + 1 < Sv) {
        xp0 = *(const float4*)(x + ((size_t)lm * Sv + (t + 1)) * Iv + xk);
        xp1 = *(const float4*)(x + ((size_t)lm * Sv + (t + 1)) * Iv + xk + 4);
      }
      __syncthreads();  // drain u-payload stores
      if (tid == 0) st32(u0s + (t & 1) * 32 + wg, (unsigned)(t + 1));
      poll1(u0s + (t & 1) * 32, (unsigned)(t + 1), tid);
      read_stage(u0d + (size_t)(t & 1) * 4096, stB, tid);
      __syncthreads();
      const unsigned short* urow = stB + lm * RP;
      v4f ag = {0, 0, 0, 0};
#pragma unroll
      for (int kb = 0; kb < 4; kb++) {
        v8bf au = *(const v8bf*)(urow + wave * 128 + kb * 32 + lq * 8);
        ag = MFMA(au, wrh[kb], ag);
      }
#pragma unroll
      for (int v = 0; v < 4; v++) red[3][wave][lq * 4 + v][lm] = ag[v];
      __syncthreads();
      float gs = 0;
#pragma unroll
      for (int w = 0; w < 4; w++) gs += red[3][w][rb][rj];
      float g = tanh_fast(xrs + gs + br);  // faithful to source bug
      float hn = z * hval + (1.f - z) * g;
      store_slice(h0d + (size_t)((t + 1) & m0) * 4096, rb, j0, rj, hn);
      if (t == Sv - 1) out[(size_t)Bv * Sv * Ov + ((size_t)rb * 2 + 0) * Hv + j0 + rj] = hn;
      __syncthreads();  // drain h-payload stores
      if (tid == 0) st32(h0s + ((t + 1) & m0) * 32 + wg, (unsigned)(t + 2));
    }
  } else {
    v8bf wzx1[4], wrx1[4], wzh[4], wrh[4], wo[4];
#pragma unroll
    for (int kb = 0; kb < 4; kb++) {
      int k = wave * 128 + kb * 32 + lq * 8;
      wzx1[kb] = cvt8(Wxz1 + (size_t)jrow * Hv + k);
      wrx1[kb] = cvt8(Wxr1 + (size_t)jrow * Hv + k);
      wzh[kb] = cvt8(Whz1 + (size_t)jrow * Hv + k);
      wrh[kb] = cvt8(Whr1 + (size_t)jrow * Hv + k);
      if (OW) wo[kb] = cvt8(Why + (size_t)jrow * Hv + k);
    }
    float bz = bhz1[j0 + rj], br = bhr1[j0 + rj];
    float bo = OW ? by[j0 + rj] : 0.f;

    for (int t = 0; t < Sv; ++t) {
      // y0_t = h0 production tag t+2 at slot (t+1)&m0; h1_t = tag t+1 at t&3
      poll2(h0s + ((t + 1) & m0) * 32, (unsigned)(t + 2),
            h1s + (t & 3) * 32, (unsigned)(t + 1), tid);
      read_stage2(h0d + (size_t)((t + 1) & m0) * 4096, stA,
                  h1d + (size_t)(t & 3) * 4096, stB, tid);
      __syncthreads();
      if (tid == 0) st32(prog + wg, (unsigned)(t + 1));  // y0_t consumed
      float hval = bf2f(stB[rb * RP + j0 + rj]);
      const unsigned short* yrow = stA + lm * RP;
      const unsigned short* hrow = stB + lm * RP;
      v4f az = {0, 0, 0, 0}, axr = {0, 0, 0, 0}, ahr = {0, 0, 0, 0}, ao = {0, 0, 0, 0};
      v8bf ahf[4];
#pragma unroll
      for (int kb = 0; kb < 4; kb++) {
        int k = wave * 128 + kb * 32 + lq * 8;
        v8bf ay = *(const v8bf*)(yrow + k);
        ahf[kb] = *(const v8bf*)(hrow + k);
        az = MFMA(ay, wzx1[kb], az);
        az = MFMA(ahf[kb], wzh[kb], az);
        axr = MFMA(ay, wrx1[kb], axr);
        ahr = MFMA(ahf[kb], wrh[kb], ahr);
      }
      if (OW && t > 0) {
#pragma unroll
        for (int kb = 0; kb < 4; kb++) ao = MFMA(ahf[kb], wo[kb], ao);  // out_{t-1}
      }
#pragma unroll
      for (int v = 0; v < 4; v++) {
        red[0][wave][lq * 4 + v][lm] = az[v];
        red[1][wave][lq * 4 + v][lm] = axr[v];
        red[2][wave][lq * 4 + v][lm] = ahr[v];
        red[3][wave][lq * 4 + v][lm] = ao[v];
      }
      __syncthreads();
      float zs = 0, xrs = 0, hrs = 0, os = 0;
#pragma unroll
      for (int w = 0; w < 4; w++) {
        zs += red[0][w][rb][rj];
        xrs += red[1][w][rb][rj];
        hrs += red[2][w][rb][rj];
        os += red[3][w][rb][rj];
      }
      float z = sigf(zs + bz);
      float r = sigf(xrs + hrs + br);
      store_slice(u1d + (t & 1) * 4096, rb, j0, rj, r * hval);
      if (OW && t > 0) out[((size_t)rb * Sv + (t - 1)) * Ov + j0 + rj] = os + bo;
      __syncthreads();
      if (tid == 0) st32(u1s + (t & 1) * 32 + wg, (unsigned)(t + 1));
      poll1(u1s + (t & 1) * 32, (unsigned)(t + 1), tid);
      read_stage(u1d + (size_t)(t & 1) * 4096, stC, tid);
      __syncthreads();
      const unsigned short* urow = stC + lm * RP;
      v4f ag = {0, 0, 0, 0};
#pragma unroll
      for (int kb = 0; kb < 4; kb++) {
        v8bf au = *(const v8bf*)(urow + wave * 128 + kb * 32 + lq * 8);
        ag = MFMA(au, wrh[kb], ag);
      }
#pragma unroll
      for (int v = 0; v < 4; v++) red[3][wave][lq * 4 + v][lm] = ag[v];
      __syncthreads();
      float gs = 0;
#pragma unroll
      for (int w = 0; w < 4; w++) gs += red[3][w][rb][rj];
      float g = tanh_fast(xrs + gs + br);
      float hn = z * hval + (1.f - z) * g;
      store_slice(h1d + (size_t)((t + 1) & 3) * 4096, rb, j0, rj, hn);
      if (t == Sv - 1) out[(size_t)Bv * Sv * Ov + ((size_t)rb * 2 + 1) * Hv + j0 + rj] = hn;
      __syncthreads();
      if (tid == 0) st32(h1s + ((t + 1) & 3) * 32 + wg, (unsigned)(t + 2));
    }
    if (OW) {  // tail: out_{S-1} from y1_{S-1} = h1 tag S+1 at slot S&3
      poll1(h1s + (Sv & 3) * 32, (unsigned)(Sv + 1), tid);
      read_stage(h1d + (size_t)(Sv & 3) * 4096, stB, tid);
      __syncthreads();
      const unsigned short* hrow = stB + lm * RP;
      v4f ao = {0, 0, 0, 0};
#pragma unroll
      for (int kb = 0; kb < 4; kb++) {
        v8bf ah = *(const v8bf*)(hrow + wave * 128 + kb * 32 + lq * 8);
        ao = MFMA(ah, wo[kb], ao);
      }
#pragma unroll
      for (int v = 0; v < 4; v++) red[3][wave][lq * 4 + v][lm] = ao[v];
      __syncthreads();
      float os = 0;
#pragma unroll
      for (int w = 0; w < 4; w++) os += red[3][w][rb][rj];
      out[((size_t)rb * Sv + (Sv - 1)) * Ov + j0 + rj] = os + bo;
    }
  }
}

extern "C" void kernel_launch(void* const* d_in, const int* in_sizes, int n_in,
                              void* d_out, int out_size, void* d_ws, size_t ws_size,
                              hipStream_t stream) {
  const float* x = (const float*)d_in[0];
  const float* hs = (const float*)d_in[1];
  const float* Wxz0 = (const float*)d_in[2];
  const float* Whz0 = (const float*)d_in[3];
  const float* bhz0 = (const float*)d_in[4];
  const float* Wxr0 = (const float*)d_in[5];
  const float* Whr0 = (const float*)d_in[6];
  const float* bhr0 = (const float*)d_in[7];
  const float* Wxz1 = (const float*)d_in[8];
  const float* Whz1 = (const float*)d_in[9];
  const float* bhz1 = (const float*)d_in[10];
  const float* Wxr1 = (const float*)d_in[11];
  const float* Whr1 = (const float*)d_in[12];
  const float* bhr1 = (const float*)d_in[13];
  const float* Why = (const float*)d_in[14];
  const float* by = (const float*)d_in[15];
  float* out = (float*)d_out;

  // y0-ring depth: largest pow2 (<=64, >=4) fitting ws
  int D = 64;
  while (D > 4 && 16384 + (size_t)(D + 8) * 16384 > ws_size) D >>= 1;

  hipMemsetAsync(d_ws, 0, 4096, stream);  // zero progress words
  hipLaunchKernelGGL(gru_fused, dim3(64), dim3(256), 0, stream,
                     x, hs, Wxz0, Whz0, bhz0, Wxr0, Whr0, bhr0,
                     Wxz1, Whz1, bhz1, Wxr1, Whr1, bhr1, Why, by,
                     out, (char*)d_ws, D);
}